// Round 5
// baseline (144.720 us; speedup 1.0000x reference)
//
#include <hip/hip_runtime.h>

constexpr int POOL  = 7;
constexpr int GRIDS = 2;
constexpr float SCALE = 0.0625f;
constexpr int C = 490, H = 100, W = 100;
constexpr int PLANE = H * W;

// Channel-major: block = (c_in, k-chunk of 256), lane = k.
// blockIdx%8 == c_lo -> all k-chunks of one c_in land on the same XCD, so the
// 4-image plane-set (160 KB) is fetched into that XCD's L2 once and reused by
// all 2048 ROIs (measured: FETCH 212 MB -> 24.6 MB in R4).
// Stores go directly to out[k*C + c_in] (scattered dwords; 4 MB output merges
// in write-back L2 — cheaper than the ws+transpose round-trip it replaces).
__global__ __launch_bounds__(256) void psroi_cmajor_kernel(
    const float* __restrict__ x, const float* __restrict__ rois,
    float* __restrict__ out, int K, int numKC)
{
    int bid  = blockIdx.x;
    int c_lo = bid & 7;
    int t    = bid >> 3;
    int kc   = t % numKC;
    int c_hi = t / numKC;
    int c_in = c_hi * 8 + c_lo;
    if (c_in >= C) return;
    int k = kc * 256 + (int)threadIdx.x;
    if (k >= K) return;

    int ph = (c_in / POOL) % POOL;
    int pw = c_in % POOL;

    const float* roi = rois + k * 5;
    int   img = (int)roi[0];
    float rx1 = roi[1] * SCALE - 0.5f;
    float ry1 = roi[2] * SCALE - 0.5f;
    float rx2 = roi[3] * SCALE - 0.5f;
    float ry2 = roi[4] * SCALE - 0.5f;
    float bsh = (ry2 - ry1) * (1.0f / POOL);
    float bsw = (rx2 - rx1) * (1.0f / POOL);

    int off0 = (img * C + c_in) * PLANE;   // < 19.6M, fits int

    // ---- per-axis pieces, branch-free ----
    int   rowlo[GRIDS], rowhi[GRIDS];
    float wyl[GRIDS], wyh[GRIDS];
    bool  vy[GRIDS];
    int   xlo[GRIDS], xhi[GRIDS];
    float wxl[GRIDS], wxh[GRIDS];
    bool  vx[GRIDS];

#pragma unroll
    for (int g = 0; g < GRIDS; ++g) {
        float yy = ry1 + ((float)ph + ((float)g + 0.5f) * (1.0f / GRIDS)) * bsh;
        vy[g] = (yy >= -1.0f) && (yy <= (float)H);
        float yc = fmaxf(yy, 0.0f);
        int lo = min((int)yc, H - 1);
        rowlo[g] = lo * W;
        rowhi[g] = min(lo + 1, H - 1) * W;
        float fy = (lo >= H - 1) ? 0.0f : (yc - (float)lo);
        wyl[g] = 1.0f - fy;
        wyh[g] = fy;

        float xxv = rx1 + ((float)pw + ((float)g + 0.5f) * (1.0f / GRIDS)) * bsw;
        vx[g] = (xxv >= -1.0f) && (xxv <= (float)W);
        float xc = fmaxf(xxv, 0.0f);
        int lo2 = min((int)xc, W - 1);
        xlo[g] = lo2;
        xhi[g] = min(lo2 + 1, W - 1);
        float fx = (lo2 >= W - 1) ? 0.0f : (xc - (float)lo2);
        wxl[g] = 1.0f - fx;
        wxh[g] = fx;
    }

    // ---- all 16 loads issued unconditionally (saddr form: uniform base +
    //      32-bit voffset), weight-zero when invalid ----
    float v[16];
#pragma unroll
    for (int gy = 0; gy < GRIDS; ++gy) {
#pragma unroll
        for (int gx = 0; gx < GRIDS; ++gx) {
            int p = (gy * GRIDS + gx) * 4;
            v[p + 0] = x[off0 + rowlo[gy] + xlo[gx]];
            v[p + 1] = x[off0 + rowlo[gy] + xhi[gx]];
            v[p + 2] = x[off0 + rowhi[gy] + xlo[gx]];
            v[p + 3] = x[off0 + rowhi[gy] + xhi[gx]];
        }
    }

    float acc = 0.0f;
#pragma unroll
    for (int gy = 0; gy < GRIDS; ++gy) {
#pragma unroll
        for (int gx = 0; gx < GRIDS; ++gx) {
            int p = (gy * GRIDS + gx) * 4;
            float w = (vy[gy] && vx[gx]) ? 0.25f : 0.0f;
            acc += w * (wyl[gy] * (wxl[gx] * v[p+0] + wxh[gx] * v[p+1])
                      + wyh[gy] * (wxl[gx] * v[p+2] + wxh[gx] * v[p+3]));
        }
    }

    out[k * C + c_in] = acc;   // scattered dword store; merges in L2 write-back
}

extern "C" void kernel_launch(void* const* d_in, const int* in_sizes, int n_in,
                              void* d_out, int out_size, void* d_ws, size_t ws_size,
                              hipStream_t stream) {
    const float* x    = (const float*)d_in[0];
    const float* rois = (const float*)d_in[1];
    float* out = (float*)d_out;

    int K = in_sizes[1] / 5;                  // 2048
    int numKC = (K + 255) / 256;              // 8
    int cGroups = (C + 7) / 8;                // 62
    int blocks = cGroups * numKC * 8;         // 3968

    psroi_cmajor_kernel<<<blocks, 256, 0, stream>>>(x, rois, out, K, numKC);
}

// Round 6
// 124.485 us; speedup vs baseline: 1.1626x; 1.1626x over previous
//
#include <hip/hip_runtime.h>

constexpr int POOL  = 7;
constexpr int GRIDS = 2;
constexpr float SCALE = 0.0625f;
constexpr int N_IMG = 4, C = 490, H = 100, W = 100;
constexpr int PLANE = H * W;                 // 10000 floats = 40 KB

// ---------------- kernel 1: bucket ROI indices by image ----------------
__global__ __launch_bounds__(256) void partition_kernel(
    const float* __restrict__ rois, int* __restrict__ lists,
    int* __restrict__ counts, int K)
{
    __shared__ int cnt[N_IMG];
    if (threadIdx.x < N_IMG) cnt[threadIdx.x] = 0;
    __syncthreads();
    for (int k = threadIdx.x; k < K; k += 256) {
        int img = (int)rois[k * 5];
        int pos = atomicAdd(&cnt[img], 1);
        lists[img * K + pos] = k;
    }
    __syncthreads();
    if (threadIdx.x < N_IMG) counts[threadIdx.x] = cnt[threadIdx.x];
}

// ------------- kernel 2: one block per (img, c_in); plane in LDS -------------
// Plane read from global exactly once (78 MB total, coalesced float4).
// 16 gathers/output hit LDS instead of L1/L2. Stores coalesced into
// ws[c_in*K + k] (transposed later).
__global__ __launch_bounds__(256) void psroi_lds_kernel(
    const float* __restrict__ x, const float* __restrict__ rois,
    float* __restrict__ wsbuf, const int* __restrict__ lists,
    const int* __restrict__ counts, int K)
{
    __shared__ float plane[PLANE];
    int bid  = blockIdx.x;
    int img  = bid & 3;
    int c_in = bid >> 2;

    const float* src = x + ((size_t)img * C + c_in) * PLANE;
    for (int i = threadIdx.x; i < PLANE / 4; i += 256)
        ((float4*)plane)[i] = ((const float4*)src)[i];
    __syncthreads();

    int ph = (c_in / POOL) % POOL;
    int pw = c_in % POOL;
    int nr = counts[img];
    const int* mylist = lists + img * K;

    for (int i = threadIdx.x; i < nr; i += 256) {
        int k = mylist[i];
        const float* roi = rois + k * 5;
        float rx1 = roi[1] * SCALE - 0.5f;
        float ry1 = roi[2] * SCALE - 0.5f;
        float rx2 = roi[3] * SCALE - 0.5f;
        float ry2 = roi[4] * SCALE - 0.5f;
        float bsh = (ry2 - ry1) * (1.0f / POOL);
        float bsw = (rx2 - rx1) * (1.0f / POOL);

        int   rowlo[GRIDS], rowhi[GRIDS];
        float wyl[GRIDS], wyh[GRIDS];
        bool  vy[GRIDS];
        int   xlo[GRIDS], xhi[GRIDS];
        float wxl[GRIDS], wxh[GRIDS];
        bool  vx[GRIDS];
#pragma unroll
        for (int g = 0; g < GRIDS; ++g) {
            float yy = ry1 + ((float)ph + ((float)g + 0.5f) * (1.0f / GRIDS)) * bsh;
            vy[g] = (yy >= -1.0f) && (yy <= (float)H);
            float yc = fmaxf(yy, 0.0f);
            int lo = min((int)yc, H - 1);
            rowlo[g] = lo * W;
            rowhi[g] = min(lo + 1, H - 1) * W;
            float fy = (lo >= H - 1) ? 0.0f : (yc - (float)lo);
            wyl[g] = 1.0f - fy;  wyh[g] = fy;

            float xxv = rx1 + ((float)pw + ((float)g + 0.5f) * (1.0f / GRIDS)) * bsw;
            vx[g] = (xxv >= -1.0f) && (xxv <= (float)W);
            float xc = fmaxf(xxv, 0.0f);
            int lo2 = min((int)xc, W - 1);
            xlo[g] = lo2;
            xhi[g] = min(lo2 + 1, W - 1);
            float fx = (lo2 >= W - 1) ? 0.0f : (xc - (float)lo2);
            wxl[g] = 1.0f - fx;  wxh[g] = fx;
        }

        float acc = 0.0f;
#pragma unroll
        for (int gy = 0; gy < GRIDS; ++gy) {
#pragma unroll
            for (int gx = 0; gx < GRIDS; ++gx) {
                float v0 = plane[rowlo[gy] + xlo[gx]];
                float v1 = plane[rowlo[gy] + xhi[gx]];
                float v2 = plane[rowhi[gy] + xlo[gx]];
                float v3 = plane[rowhi[gy] + xhi[gx]];
                float w = (vy[gy] && vx[gx]) ? 0.25f : 0.0f;
                acc += w * (wyl[gy] * (wxl[gx] * v0 + wxh[gx] * v1)
                          + wyh[gy] * (wxl[gx] * v2 + wxh[gx] * v3));
            }
        }
        wsbuf[c_in * K + k] = acc;
    }
}

// ------------- kernel 3: tiled transpose ws[c*K+k] -> out[k*C+c] -------------
__global__ __launch_bounds__(256) void transpose_kernel(
    const float* __restrict__ wsbuf, float* __restrict__ out, int K)
{
    __shared__ float tile[32][33];
    int cb = blockIdx.x % 16;            // ceil(490/32) = 16
    int kb = blockIdx.x / 16;            // K/32 blocks
    int c0 = cb * 32, k0 = kb * 32;
    int tx = threadIdx.x & 31, ty = threadIdx.x >> 5;   // 8 rows/pass

    for (int r = ty; r < 32; r += 8) {
        int c = c0 + r;
        tile[r][tx] = (c < C) ? wsbuf[c * K + k0 + tx] : 0.0f;
    }
    __syncthreads();
    for (int r = ty; r < 32; r += 8) {
        int c = c0 + tx;
        if (c < C) out[(k0 + r) * C + c] = tile[tx][r];
    }
}

// ------------- fallback (ws too small): R5 direct-store kernel -------------
__global__ __launch_bounds__(256) void psroi_direct_kernel(
    const float* __restrict__ x, const float* __restrict__ rois,
    float* __restrict__ out, int K, int numKC)
{
    int bid  = blockIdx.x;
    int c_lo = bid & 7;
    int t    = bid >> 3;
    int kc   = t % numKC;
    int c_hi = t / numKC;
    int c_in = c_hi * 8 + c_lo;
    if (c_in >= C) return;
    int k = kc * 256 + (int)threadIdx.x;
    if (k >= K) return;

    int ph = (c_in / POOL) % POOL;
    int pw = c_in % POOL;
    const float* roi = rois + k * 5;
    int   img = (int)roi[0];
    float rx1 = roi[1] * SCALE - 0.5f;
    float ry1 = roi[2] * SCALE - 0.5f;
    float rx2 = roi[3] * SCALE - 0.5f;
    float ry2 = roi[4] * SCALE - 0.5f;
    float bsh = (ry2 - ry1) * (1.0f / POOL);
    float bsw = (rx2 - rx1) * (1.0f / POOL);
    int off0 = (img * C + c_in) * PLANE;

    float acc = 0.0f;
#pragma unroll
    for (int gy = 0; gy < GRIDS; ++gy) {
        float yy = ry1 + ((float)ph + ((float)gy + 0.5f) * (1.0f / GRIDS)) * bsh;
        bool vy = (yy >= -1.0f) && (yy <= (float)H);
        float yc = fmaxf(yy, 0.0f);
        int lo = min((int)yc, H - 1);
        int rl = lo * W, rh = min(lo + 1, H - 1) * W;
        float fy = (lo >= H - 1) ? 0.0f : (yc - (float)lo);
#pragma unroll
        for (int gx = 0; gx < GRIDS; ++gx) {
            float xxv = rx1 + ((float)pw + ((float)gx + 0.5f) * (1.0f / GRIDS)) * bsw;
            bool vx = (xxv >= -1.0f) && (xxv <= (float)W);
            float xc = fmaxf(xxv, 0.0f);
            int lo2 = min((int)xc, W - 1);
            int xh = min(lo2 + 1, W - 1);
            float fx = (lo2 >= W - 1) ? 0.0f : (xc - (float)lo2);
            float w = (vy && vx) ? 0.25f : 0.0f;
            acc += w * ((1.0f - fy) * ((1.0f - fx) * x[off0 + rl + lo2] + fx * x[off0 + rl + xh])
                      + fy          * ((1.0f - fx) * x[off0 + rh + lo2] + fx * x[off0 + rh + xh]));
        }
    }
    out[k * C + c_in] = acc;
}

extern "C" void kernel_launch(void* const* d_in, const int* in_sizes, int n_in,
                              void* d_out, int out_size, void* d_ws, size_t ws_size,
                              hipStream_t stream) {
    const float* x    = (const float*)d_in[0];
    const float* rois = (const float*)d_in[1];
    float* out = (float*)d_out;
    int K = in_sizes[1] / 5;                              // 2048

    size_t wsbuf_bytes = (size_t)C * K * sizeof(float);   // 4,014,080
    size_t lists_bytes = (size_t)N_IMG * K * sizeof(int); // 32,768
    size_t need = wsbuf_bytes + lists_bytes + N_IMG * sizeof(int);

    if (ws_size >= need && (K % 32) == 0) {
        float* wsbuf  = (float*)d_ws;
        int*   lists  = (int*)((char*)d_ws + wsbuf_bytes);
        int*   counts = (int*)((char*)d_ws + wsbuf_bytes + lists_bytes);

        partition_kernel<<<1, 256, 0, stream>>>(rois, lists, counts, K);
        psroi_lds_kernel<<<N_IMG * C, 256, 0, stream>>>(x, rois, wsbuf, lists, counts, K);
        transpose_kernel<<<16 * (K / 32), 256, 0, stream>>>(wsbuf, out, K);
    } else {
        int numKC = (K + 255) / 256;
        int blocks = ((C + 7) / 8) * numKC * 8;
        psroi_direct_kernel<<<blocks, 256, 0, stream>>>(x, rois, out, K, numKC);
    }
}

// Round 7
// 120.866 us; speedup vs baseline: 1.1974x; 1.0299x over previous
//
#include <hip/hip_runtime.h>

constexpr int POOL  = 7;
constexpr int GRIDS = 2;
constexpr float SCALE = 0.0625f;
constexpr int N_IMG = 4, C = 490, H = 100, W = 100;
constexpr int PLANE = H * W;                 // 10000 floats = 40 KB
constexpr int N16   = PLANE / 4;             // 2500 16-byte lane-transfers

// ---------------- kernel 1: bucket ROI indices by image ----------------
__global__ __launch_bounds__(256) void partition_kernel(
    const float* __restrict__ rois, int* __restrict__ lists,
    int* __restrict__ counts, int K)
{
    __shared__ int cnt[N_IMG];
    if (threadIdx.x < N_IMG) cnt[threadIdx.x] = 0;
    __syncthreads();
    for (int k = threadIdx.x; k < K; k += 256) {
        int img = (int)rois[k * 5];
        int pos = atomicAdd(&cnt[img], 1);
        lists[img * K + pos] = k;
    }
    __syncthreads();
    if (threadIdx.x < N_IMG) counts[threadIdx.x] = cnt[threadIdx.x];
}

// ------------- kernel 2: one block per (img, c_in); plane in LDS -------------
// Staging via global_load_lds width=16 (direct HBM->LDS, no VGPR round-trip).
// Layout satisfies the wave-uniform-base + lane*16 constraint: wave chunk c
// covers plane[c*256 .. c*256+255] from src + same offsets.
__global__ __launch_bounds__(256) void psroi_lds_kernel(
    const float* __restrict__ x, const float* __restrict__ rois,
    float* __restrict__ wsbuf, const int* __restrict__ lists,
    const int* __restrict__ counts, int K)
{
    __shared__ float plane[PLANE];
    int bid  = blockIdx.x;
    int img  = bid & 3;
    int c_in = bid >> 2;

    const float* src = x + ((size_t)img * C + c_in) * PLANE;
    int lane = threadIdx.x & 63;
    int wave = threadIdx.x >> 6;
    // 2500 lane-transfers of 16B; 64 per wave-instruction -> 40 chunks (last partial)
    for (int chunk = wave; chunk * 64 < N16; chunk += 4) {
        int t16 = chunk * 64 + lane;                 // 16B-transfer index
        if (t16 < N16) {
            const float* g = src + t16 * 4;
            __builtin_amdgcn_global_load_lds(
                (const __attribute__((address_space(1))) void*)g,
                (__attribute__((address_space(3))) void*)(plane + chunk * 256),
                16, 0, 0);
        }
    }
    __syncthreads();   // drains vmcnt for the LDS-bound loads

    int ph = (c_in / POOL) % POOL;
    int pw = c_in % POOL;
    int nr = counts[img];
    const int* mylist = lists + img * K;

    for (int i = threadIdx.x; i < nr; i += 256) {
        int k = mylist[i];
        const float* roi = rois + k * 5;
        float rx1 = roi[1] * SCALE - 0.5f;
        float ry1 = roi[2] * SCALE - 0.5f;
        float rx2 = roi[3] * SCALE - 0.5f;
        float ry2 = roi[4] * SCALE - 0.5f;
        float bsh = (ry2 - ry1) * (1.0f / POOL);
        float bsw = (rx2 - rx1) * (1.0f / POOL);

        int   rowlo[GRIDS], rowhi[GRIDS];
        float wyl[GRIDS], wyh[GRIDS];
        bool  vy[GRIDS];
        int   xlo[GRIDS], xhi[GRIDS];
        float wxl[GRIDS], wxh[GRIDS];
        bool  vx[GRIDS];
#pragma unroll
        for (int g = 0; g < GRIDS; ++g) {
            float yy = ry1 + ((float)ph + ((float)g + 0.5f) * (1.0f / GRIDS)) * bsh;
            vy[g] = (yy >= -1.0f) && (yy <= (float)H);
            float yc = fmaxf(yy, 0.0f);
            int lo = min((int)yc, H - 1);
            rowlo[g] = lo * W;
            rowhi[g] = min(lo + 1, H - 1) * W;
            float fy = (lo >= H - 1) ? 0.0f : (yc - (float)lo);
            wyl[g] = 1.0f - fy;  wyh[g] = fy;

            float xxv = rx1 + ((float)pw + ((float)g + 0.5f) * (1.0f / GRIDS)) * bsw;
            vx[g] = (xxv >= -1.0f) && (xxv <= (float)W);
            float xc = fmaxf(xxv, 0.0f);
            int lo2 = min((int)xc, W - 1);
            xlo[g] = lo2;
            xhi[g] = min(lo2 + 1, W - 1);
            float fx = (lo2 >= W - 1) ? 0.0f : (xc - (float)lo2);
            wxl[g] = 1.0f - fx;  wxh[g] = fx;
        }

        float acc = 0.0f;
#pragma unroll
        for (int gy = 0; gy < GRIDS; ++gy) {
#pragma unroll
            for (int gx = 0; gx < GRIDS; ++gx) {
                float v0 = plane[rowlo[gy] + xlo[gx]];
                float v1 = plane[rowlo[gy] + xhi[gx]];
                float v2 = plane[rowhi[gy] + xlo[gx]];
                float v3 = plane[rowhi[gy] + xhi[gx]];
                float w = (vy[gy] && vx[gx]) ? 0.25f : 0.0f;
                acc += w * (wyl[gy] * (wxl[gx] * v0 + wxh[gx] * v1)
                          + wyh[gy] * (wxl[gx] * v2 + wxh[gx] * v3));
            }
        }
        wsbuf[c_in * K + k] = acc;
    }
}

// ------------- kernel 3: tiled transpose ws[c*K+k] -> out[k*C+c] -------------
__global__ __launch_bounds__(256) void transpose_kernel(
    const float* __restrict__ wsbuf, float* __restrict__ out, int K)
{
    __shared__ float tile[32][33];
    int cb = blockIdx.x % 16;            // ceil(490/32) = 16
    int kb = blockIdx.x / 16;            // K/32 blocks
    int c0 = cb * 32, k0 = kb * 32;
    int tx = threadIdx.x & 31, ty = threadIdx.x >> 5;   // 8 rows/pass

    for (int r = ty; r < 32; r += 8) {
        int c = c0 + r;
        tile[r][tx] = (c < C) ? wsbuf[c * K + k0 + tx] : 0.0f;
    }
    __syncthreads();
    for (int r = ty; r < 32; r += 8) {
        int c = c0 + tx;
        if (c < C) out[(k0 + r) * C + c] = tile[tx][r];
    }
}

// ------------- fallback (ws too small): direct-store kernel -------------
__global__ __launch_bounds__(256) void psroi_direct_kernel(
    const float* __restrict__ x, const float* __restrict__ rois,
    float* __restrict__ out, int K, int numKC)
{
    int bid  = blockIdx.x;
    int c_lo = bid & 7;
    int t    = bid >> 3;
    int kc   = t % numKC;
    int c_hi = t / numKC;
    int c_in = c_hi * 8 + c_lo;
    if (c_in >= C) return;
    int k = kc * 256 + (int)threadIdx.x;
    if (k >= K) return;

    int ph = (c_in / POOL) % POOL;
    int pw = c_in % POOL;
    const float* roi = rois + k * 5;
    int   img = (int)roi[0];
    float rx1 = roi[1] * SCALE - 0.5f;
    float ry1 = roi[2] * SCALE - 0.5f;
    float rx2 = roi[3] * SCALE - 0.5f;
    float ry2 = roi[4] * SCALE - 0.5f;
    float bsh = (ry2 - ry1) * (1.0f / POOL);
    float bsw = (rx2 - rx1) * (1.0f / POOL);
    int off0 = (img * C + c_in) * PLANE;

    float acc = 0.0f;
#pragma unroll
    for (int gy = 0; gy < GRIDS; ++gy) {
        float yy = ry1 + ((float)ph + ((float)gy + 0.5f) * (1.0f / GRIDS)) * bsh;
        bool vy = (yy >= -1.0f) && (yy <= (float)H);
        float yc = fmaxf(yy, 0.0f);
        int lo = min((int)yc, H - 1);
        int rl = lo * W, rh = min(lo + 1, H - 1) * W;
        float fy = (lo >= H - 1) ? 0.0f : (yc - (float)lo);
#pragma unroll
        for (int gx = 0; gx < GRIDS; ++gx) {
            float xxv = rx1 + ((float)pw + ((float)gx + 0.5f) * (1.0f / GRIDS)) * bsw;
            bool vx = (xxv >= -1.0f) && (xxv <= (float)W);
            float xc = fmaxf(xxv, 0.0f);
            int lo2 = min((int)xc, W - 1);
            int xh = min(lo2 + 1, W - 1);
            float fx = (lo2 >= W - 1) ? 0.0f : (xc - (float)lo2);
            float w = (vy && vx) ? 0.25f : 0.0f;
            acc += w * ((1.0f - fy) * ((1.0f - fx) * x[off0 + rl + lo2] + fx * x[off0 + rl + xh])
                      + fy          * ((1.0f - fx) * x[off0 + rh + lo2] + fx * x[off0 + rh + xh]));
        }
    }
    out[k * C + c_in] = acc;
}

extern "C" void kernel_launch(void* const* d_in, const int* in_sizes, int n_in,
                              void* d_out, int out_size, void* d_ws, size_t ws_size,
                              hipStream_t stream) {
    const float* x    = (const float*)d_in[0];
    const float* rois = (const float*)d_in[1];
    float* out = (float*)d_out;
    int K = in_sizes[1] / 5;                              // 2048

    size_t wsbuf_bytes = (size_t)C * K * sizeof(float);   // 4,014,080
    size_t lists_bytes = (size_t)N_IMG * K * sizeof(int); // 32,768
    size_t need = wsbuf_bytes + lists_bytes + N_IMG * sizeof(int);

    if (ws_size >= need && (K % 32) == 0) {
        float* wsbuf  = (float*)d_ws;
        int*   lists  = (int*)((char*)d_ws + wsbuf_bytes);
        int*   counts = (int*)((char*)d_ws + wsbuf_bytes + lists_bytes);

        partition_kernel<<<1, 256, 0, stream>>>(rois, lists, counts, K);
        psroi_lds_kernel<<<N_IMG * C, 256, 0, stream>>>(x, rois, wsbuf, lists, counts, K);
        transpose_kernel<<<16 * (K / 32), 256, 0, stream>>>(wsbuf, out, K);
    } else {
        int numKC = (K + 255) / 256;
        int blocks = ((C + 7) / 8) * numKC * 8;
        psroi_direct_kernel<<<blocks, 256, 0, stream>>>(x, rois, out, K, numKC);
    }
}

// Round 8
// 116.507 us; speedup vs baseline: 1.2422x; 1.0374x over previous
//
#include <hip/hip_runtime.h>

constexpr int POOL  = 7;
constexpr int GRIDS = 2;
constexpr float SCALE = 0.0625f;
constexpr int N_IMG = 4, C = 490, H = 100, W = 100;
constexpr int PLANE = H * W;                 // 10000 floats = 40 KB
constexpr int N16   = PLANE / 4;             // 2500 16-byte lane-transfers/plane

// ---- kernel: one block per c_in; ALL 4 images' planes staged in 160 KB LDS.
// No ROI partitioning needed: a lane's img index is just an LDS base offset,
// so all 64 lanes are always active and ws-stores (k = loop index) are
// perfectly coalesced. Each plane is fetched from global exactly once.
__global__ __launch_bounds__(256) void psroi_lds4_kernel(
    const float* __restrict__ x, const float* __restrict__ rois,
    float* __restrict__ wsbuf, int K)
{
    __shared__ float plane4[N_IMG * PLANE];  // 160000 B (gfx950 LDS = 163840 B)
    int c_in = blockIdx.x;

    int lane = threadIdx.x & 63;
    int wave = threadIdx.x >> 6;
    // stage 4 planes via async global_load_lds width=16 (wave-uniform dst base)
    for (int img = 0; img < N_IMG; ++img) {
        const float* src = x + ((size_t)img * C + c_in) * PLANE;
        float* dstbase = plane4 + img * PLANE;
        for (int chunk = wave; chunk * 64 < N16; chunk += 4) {
            int t16 = chunk * 64 + lane;
            if (t16 < N16) {
                __builtin_amdgcn_global_load_lds(
                    (const __attribute__((address_space(1))) void*)(src + t16 * 4),
                    (__attribute__((address_space(3))) void*)(dstbase + chunk * 256),
                    16, 0, 0);
            }
        }
    }
    __syncthreads();   // drains vmcnt for LDS-bound loads

    int ph = (c_in / POOL) % POOL;           // block-uniform
    int pw = c_in % POOL;

    for (int k = threadIdx.x; k < K; k += 256) {
        const float* roi = rois + k * 5;
        int   img = (int)roi[0];
        float rx1 = roi[1] * SCALE - 0.5f;
        float ry1 = roi[2] * SCALE - 0.5f;
        float rx2 = roi[3] * SCALE - 0.5f;
        float ry2 = roi[4] * SCALE - 0.5f;
        float bsh = (ry2 - ry1) * (1.0f / POOL);
        float bsw = (rx2 - rx1) * (1.0f / POOL);
        const float* pl = plane4 + img * PLANE;   // per-lane LDS base

        int   rowlo[GRIDS], rowhi[GRIDS];
        float wyl[GRIDS], wyh[GRIDS];
        bool  vy[GRIDS];
        int   xlo[GRIDS], xhi[GRIDS];
        float wxl[GRIDS], wxh[GRIDS];
        bool  vx[GRIDS];
#pragma unroll
        for (int g = 0; g < GRIDS; ++g) {
            float yy = ry1 + ((float)ph + ((float)g + 0.5f) * (1.0f / GRIDS)) * bsh;
            vy[g] = (yy >= -1.0f) && (yy <= (float)H);
            float yc = fmaxf(yy, 0.0f);
            int lo = min((int)yc, H - 1);
            rowlo[g] = lo * W;
            rowhi[g] = min(lo + 1, H - 1) * W;
            float fy = (lo >= H - 1) ? 0.0f : (yc - (float)lo);
            wyl[g] = 1.0f - fy;  wyh[g] = fy;

            float xxv = rx1 + ((float)pw + ((float)g + 0.5f) * (1.0f / GRIDS)) * bsw;
            vx[g] = (xxv >= -1.0f) && (xxv <= (float)W);
            float xc = fmaxf(xxv, 0.0f);
            int lo2 = min((int)xc, W - 1);
            xlo[g] = lo2;
            xhi[g] = min(lo2 + 1, W - 1);
            float fx = (lo2 >= W - 1) ? 0.0f : (xc - (float)lo2);
            wxl[g] = 1.0f - fx;  wxh[g] = fx;
        }

        float acc = 0.0f;
#pragma unroll
        for (int gy = 0; gy < GRIDS; ++gy) {
#pragma unroll
            for (int gx = 0; gx < GRIDS; ++gx) {
                float v0 = pl[rowlo[gy] + xlo[gx]];
                float v1 = pl[rowlo[gy] + xhi[gx]];
                float v2 = pl[rowhi[gy] + xlo[gx]];
                float v3 = pl[rowhi[gy] + xhi[gx]];
                float w = (vy[gy] && vx[gx]) ? 0.25f : 0.0f;
                acc += w * (wyl[gy] * (wxl[gx] * v0 + wxh[gx] * v1)
                          + wyh[gy] * (wxl[gx] * v2 + wxh[gx] * v3));
            }
        }
        wsbuf[c_in * K + k] = acc;   // coalesced
    }
}

// ------------- tiled transpose ws[c*K+k] -> out[k*C+c] -------------
__global__ __launch_bounds__(256) void transpose_kernel(
    const float* __restrict__ wsbuf, float* __restrict__ out, int K)
{
    __shared__ float tile[32][33];
    int cb = blockIdx.x % 16;            // ceil(490/32) = 16
    int kb = blockIdx.x / 16;
    int c0 = cb * 32, k0 = kb * 32;
    int tx = threadIdx.x & 31, ty = threadIdx.x >> 5;

    for (int r = ty; r < 32; r += 8) {
        int c = c0 + r;
        tile[r][tx] = (c < C) ? wsbuf[c * K + k0 + tx] : 0.0f;
    }
    __syncthreads();
    for (int r = ty; r < 32; r += 8) {
        int c = c0 + tx;
        if (c < C) out[(k0 + r) * C + c] = tile[tx][r];
    }
}

// ------------- fallback (ws too small): direct-store kernel -------------
__global__ __launch_bounds__(256) void psroi_direct_kernel(
    const float* __restrict__ x, const float* __restrict__ rois,
    float* __restrict__ out, int K, int numKC)
{
    int bid  = blockIdx.x;
    int c_lo = bid & 7;
    int t    = bid >> 3;
    int kc   = t % numKC;
    int c_hi = t / numKC;
    int c_in = c_hi * 8 + c_lo;
    if (c_in >= C) return;
    int k = kc * 256 + (int)threadIdx.x;
    if (k >= K) return;

    int ph = (c_in / POOL) % POOL;
    int pw = c_in % POOL;
    const float* roi = rois + k * 5;
    int   img = (int)roi[0];
    float rx1 = roi[1] * SCALE - 0.5f;
    float ry1 = roi[2] * SCALE - 0.5f;
    float rx2 = roi[3] * SCALE - 0.5f;
    float ry2 = roi[4] * SCALE - 0.5f;
    float bsh = (ry2 - ry1) * (1.0f / POOL);
    float bsw = (rx2 - rx1) * (1.0f / POOL);
    int off0 = (img * C + c_in) * PLANE;

    float acc = 0.0f;
#pragma unroll
    for (int gy = 0; gy < GRIDS; ++gy) {
        float yy = ry1 + ((float)ph + ((float)gy + 0.5f) * (1.0f / GRIDS)) * bsh;
        bool vy = (yy >= -1.0f) && (yy <= (float)H);
        float yc = fmaxf(yy, 0.0f);
        int lo = min((int)yc, H - 1);
        int rl = lo * W, rh = min(lo + 1, H - 1) * W;
        float fy = (lo >= H - 1) ? 0.0f : (yc - (float)lo);
#pragma unroll
        for (int gx = 0; gx < GRIDS; ++gx) {
            float xxv = rx1 + ((float)pw + ((float)gx + 0.5f) * (1.0f / GRIDS)) * bsw;
            bool vx = (xxv >= -1.0f) && (xxv <= (float)W);
            float xc = fmaxf(xxv, 0.0f);
            int lo2 = min((int)xc, W - 1);
            int xh = min(lo2 + 1, W - 1);
            float fx = (lo2 >= W - 1) ? 0.0f : (xc - (float)lo2);
            float w = (vy && vx) ? 0.25f : 0.0f;
            acc += w * ((1.0f - fy) * ((1.0f - fx) * x[off0 + rl + lo2] + fx * x[off0 + rl + xh])
                      + fy          * ((1.0f - fx) * x[off0 + rh + lo2] + fx * x[off0 + rh + xh]));
        }
    }
    out[k * C + c_in] = acc;
}

extern "C" void kernel_launch(void* const* d_in, const int* in_sizes, int n_in,
                              void* d_out, int out_size, void* d_ws, size_t ws_size,
                              hipStream_t stream) {
    const float* x    = (const float*)d_in[0];
    const float* rois = (const float*)d_in[1];
    float* out = (float*)d_out;
    int K = in_sizes[1] / 5;                              // 2048

    size_t wsbuf_bytes = (size_t)C * K * sizeof(float);   // 4,014,080

    if (ws_size >= wsbuf_bytes && (K % 32) == 0) {
        float* wsbuf = (float*)d_ws;
        psroi_lds4_kernel<<<C, 256, 0, stream>>>(x, rois, wsbuf, K);
        transpose_kernel<<<16 * (K / 32), 256, 0, stream>>>(wsbuf, out, K);
    } else {
        int numKC = (K + 255) / 256;
        int blocks = ((C + 7) / 8) * numKC * 8;
        psroi_direct_kernel<<<blocks, 256, 0, stream>>>(x, rois, out, K, numKC);
    }
}

// Round 9
// 114.065 us; speedup vs baseline: 1.2688x; 1.0214x over previous
//
#include <hip/hip_runtime.h>

constexpr int POOL  = 7;
constexpr int GRIDS = 2;
constexpr float SCALE = 0.0625f;
constexpr int N_IMG = 4, C = 490, H = 100, W = 100;
constexpr int PLANE = H * W;                 // 10000 floats = 40 KB
constexpr int N16   = PLANE / 4;             // 2500 16-byte lane-transfers/plane
constexpr int NTHR  = 1024;                  // 16 waves
constexpr int NWAVE = NTHR / 64;
constexpr int MAX_IT = 2;                    // K <= NTHR*MAX_IT handled here

// ---- kernel: one block per c_in; ALL 4 images' planes staged in 160 KB LDS.
// 16 waves: 4x staging issue rate + latency hiding vs R8's 4 waves. Each
// thread prefetches its ROI records into registers BEFORE the barrier so the
// post-barrier phase is pure LDS+VALU. Stores to ws are coalesced.
__global__ __launch_bounds__(NTHR) void psroi_lds4_kernel(
    const float* __restrict__ x, const float* __restrict__ rois,
    float* __restrict__ wsbuf, int K)
{
    __shared__ float plane4[N_IMG * PLANE];  // 160000 B (gfx950 LDS = 163840 B)
    int c_in = blockIdx.x;

    int lane = threadIdx.x & 63;
    int wave = threadIdx.x >> 6;

    // stage 4 planes via async global_load_lds width=16 (wave-uniform dst base)
#pragma unroll
    for (int img = 0; img < N_IMG; ++img) {
        const float* src = x + ((size_t)img * C + c_in) * PLANE;
        float* dstbase = plane4 + img * PLANE;
        for (int chunk = wave; chunk * 64 < N16; chunk += NWAVE) {
            int t16 = chunk * 64 + lane;
            if (t16 < N16) {
                __builtin_amdgcn_global_load_lds(
                    (const __attribute__((address_space(1))) void*)(src + t16 * 4),
                    (__attribute__((address_space(3))) void*)(dstbase + chunk * 256),
                    16, 0, 0);
            }
        }
    }

    // prefetch my ROI records while the DMA streams (no LDS dependence)
    float rp[MAX_IT][5];
    int nit = 0;
    for (int k = threadIdx.x; k < K && nit < MAX_IT; k += NTHR, ++nit) {
        const float* roi = rois + (size_t)k * 5;
        rp[nit][0] = roi[0]; rp[nit][1] = roi[1]; rp[nit][2] = roi[2];
        rp[nit][3] = roi[3]; rp[nit][4] = roi[4];
    }

    __syncthreads();   // drains vmcnt for LDS-bound loads

    int ph = (c_in / POOL) % POOL;           // block-uniform
    int pw = c_in % POOL;

    for (int it = 0; it < nit; ++it) {
        int k = threadIdx.x + it * NTHR;
        int   img = (int)rp[it][0];
        float rx1 = rp[it][1] * SCALE - 0.5f;
        float ry1 = rp[it][2] * SCALE - 0.5f;
        float rx2 = rp[it][3] * SCALE - 0.5f;
        float ry2 = rp[it][4] * SCALE - 0.5f;
        float bsh = (ry2 - ry1) * (1.0f / POOL);
        float bsw = (rx2 - rx1) * (1.0f / POOL);
        const float* pl = plane4 + img * PLANE;   // per-lane LDS base

        int   rowlo[GRIDS], rowhi[GRIDS];
        float wyl[GRIDS], wyh[GRIDS];
        bool  vy[GRIDS];
        int   xlo[GRIDS], xhi[GRIDS];
        float wxl[GRIDS], wxh[GRIDS];
        bool  vx[GRIDS];
#pragma unroll
        for (int g = 0; g < GRIDS; ++g) {
            float yy = ry1 + ((float)ph + ((float)g + 0.5f) * (1.0f / GRIDS)) * bsh;
            vy[g] = (yy >= -1.0f) && (yy <= (float)H);
            float yc = fmaxf(yy, 0.0f);
            int lo = min((int)yc, H - 1);
            rowlo[g] = lo * W;
            rowhi[g] = min(lo + 1, H - 1) * W;
            float fy = (lo >= H - 1) ? 0.0f : (yc - (float)lo);
            wyl[g] = 1.0f - fy;  wyh[g] = fy;

            float xxv = rx1 + ((float)pw + ((float)g + 0.5f) * (1.0f / GRIDS)) * bsw;
            vx[g] = (xxv >= -1.0f) && (xxv <= (float)W);
            float xc = fmaxf(xxv, 0.0f);
            int lo2 = min((int)xc, W - 1);
            xlo[g] = lo2;
            xhi[g] = min(lo2 + 1, W - 1);
            float fx = (lo2 >= W - 1) ? 0.0f : (xc - (float)lo2);
            wxl[g] = 1.0f - fx;  wxh[g] = fx;
        }

        float acc = 0.0f;
#pragma unroll
        for (int gy = 0; gy < GRIDS; ++gy) {
#pragma unroll
            for (int gx = 0; gx < GRIDS; ++gx) {
                float v0 = pl[rowlo[gy] + xlo[gx]];
                float v1 = pl[rowlo[gy] + xhi[gx]];
                float v2 = pl[rowhi[gy] + xlo[gx]];
                float v3 = pl[rowhi[gy] + xhi[gx]];
                float w = (vy[gy] && vx[gx]) ? 0.25f : 0.0f;
                acc += w * (wyl[gy] * (wxl[gx] * v0 + wxh[gx] * v1)
                          + wyh[gy] * (wxl[gx] * v2 + wxh[gx] * v3));
            }
        }
        wsbuf[c_in * K + k] = acc;   // coalesced
    }
}

// ------------- tiled transpose ws[c*K+k] -> out[k*C+c] -------------
__global__ __launch_bounds__(256) void transpose_kernel(
    const float* __restrict__ wsbuf, float* __restrict__ out, int K)
{
    __shared__ float tile[32][33];
    int cb = blockIdx.x % 16;            // ceil(490/32) = 16
    int kb = blockIdx.x / 16;
    int c0 = cb * 32, k0 = kb * 32;
    int tx = threadIdx.x & 31, ty = threadIdx.x >> 5;

    for (int r = ty; r < 32; r += 8) {
        int c = c0 + r;
        tile[r][tx] = (c < C) ? wsbuf[c * K + k0 + tx] : 0.0f;
    }
    __syncthreads();
    for (int r = ty; r < 32; r += 8) {
        int c = c0 + tx;
        if (c < C) out[(k0 + r) * C + c] = tile[tx][r];
    }
}

// ------------- fallback: direct-store kernel -------------
__global__ __launch_bounds__(256) void psroi_direct_kernel(
    const float* __restrict__ x, const float* __restrict__ rois,
    float* __restrict__ out, int K, int numKC)
{
    int bid  = blockIdx.x;
    int c_lo = bid & 7;
    int t    = bid >> 3;
    int kc   = t % numKC;
    int c_hi = t / numKC;
    int c_in = c_hi * 8 + c_lo;
    if (c_in >= C) return;
    int k = kc * 256 + (int)threadIdx.x;
    if (k >= K) return;

    int ph = (c_in / POOL) % POOL;
    int pw = c_in % POOL;
    const float* roi = rois + (size_t)k * 5;
    int   img = (int)roi[0];
    float rx1 = roi[1] * SCALE - 0.5f;
    float ry1 = roi[2] * SCALE - 0.5f;
    float rx2 = roi[3] * SCALE - 0.5f;
    float ry2 = roi[4] * SCALE - 0.5f;
    float bsh = (ry2 - ry1) * (1.0f / POOL);
    float bsw = (rx2 - rx1) * (1.0f / POOL);
    int off0 = (img * C + c_in) * PLANE;

    float acc = 0.0f;
#pragma unroll
    for (int gy = 0; gy < GRIDS; ++gy) {
        float yy = ry1 + ((float)ph + ((float)gy + 0.5f) * (1.0f / GRIDS)) * bsh;
        bool vy = (yy >= -1.0f) && (yy <= (float)H);
        float yc = fmaxf(yy, 0.0f);
        int lo = min((int)yc, H - 1);
        int rl = lo * W, rh = min(lo + 1, H - 1) * W;
        float fy = (lo >= H - 1) ? 0.0f : (yc - (float)lo);
#pragma unroll
        for (int gx = 0; gx < GRIDS; ++gx) {
            float xxv = rx1 + ((float)pw + ((float)gx + 0.5f) * (1.0f / GRIDS)) * bsw;
            bool vx = (xxv >= -1.0f) && (xxv <= (float)W);
            float xc = fmaxf(xxv, 0.0f);
            int lo2 = min((int)xc, W - 1);
            int xh = min(lo2 + 1, W - 1);
            float fx = (lo2 >= W - 1) ? 0.0f : (xc - (float)lo2);
            float w = (vy && vx) ? 0.25f : 0.0f;
            acc += w * ((1.0f - fy) * ((1.0f - fx) * x[off0 + rl + lo2] + fx * x[off0 + rl + xh])
                      + fy          * ((1.0f - fx) * x[off0 + rh + lo2] + fx * x[off0 + rh + xh]));
        }
    }
    out[k * C + c_in] = acc;
}

extern "C" void kernel_launch(void* const* d_in, const int* in_sizes, int n_in,
                              void* d_out, int out_size, void* d_ws, size_t ws_size,
                              hipStream_t stream) {
    const float* x    = (const float*)d_in[0];
    const float* rois = (const float*)d_in[1];
    float* out = (float*)d_out;
    int K = in_sizes[1] / 5;                              // 2048

    size_t wsbuf_bytes = (size_t)C * K * sizeof(float);   // 4,014,080

    if (ws_size >= wsbuf_bytes && (K % 32) == 0 && K <= NTHR * MAX_IT) {
        float* wsbuf = (float*)d_ws;
        psroi_lds4_kernel<<<C, NTHR, 0, stream>>>(x, rois, wsbuf, K);
        transpose_kernel<<<16 * (K / 32), 256, 0, stream>>>(wsbuf, out, K);
    } else {
        int numKC = (K + 255) / 256;
        int blocks = ((C + 7) / 8) * numKC * 8;
        psroi_direct_kernel<<<blocks, 256, 0, stream>>>(x, rois, out, K, numKC);
    }
}